// Round 1
// baseline (878.122 us; speedup 1.0000x reference)
//
#include <hip/hip_runtime.h>
#include <math.h>

#define B_   16
#define S_   8192
#define KVD  512
#define E_   512
#define H_   8
#define D_   64

// ---------------------------------------------------------------------------
// Kernel A: q = (query@Wq + bq) * 1/sqrt(D), folded into per-head kv-space
// vectors: qk_vec[b][h][c] = sum_d q[b,h*64+d] * Wk[c][h*64+d]
// (bk is softmax-invariant per (b,h) -> dropped)
// ---------------------------------------------------------------------------
__global__ __launch_bounds__(512) void k_fold(const float* __restrict__ query,
                                              const float* __restrict__ Wq,
                                              const float* __restrict__ bq,
                                              const float* __restrict__ Wk,
                                              float* __restrict__ qk_vec) {
    int b = blockIdx.x;
    int tid = threadIdx.x;
    __shared__ float qs[E_];

    // phase 1: q[b][e], coalesced over e
    {
        int e = tid;
        float acc = bq[e];
        const float* qrow = query + b * 512;  // Q_DIM = 512
        for (int i = 0; i < 512; ++i)
            acc = fmaf(qrow[i], Wq[i * E_ + e], acc);
        qs[e] = acc * 0.125f;  // 1/sqrt(64) folded here
    }
    __syncthreads();

    // phase 2: fold into kv space; thread = column c
    {
        int c = tid;
        const float* wkr = Wk + (size_t)c * E_;
        for (int h = 0; h < H_; ++h) {
            float a = 0.f;
            #pragma unroll
            for (int d = 0; d < D_; ++d)
                a = fmaf(qs[h * D_ + d], wkr[h * D_ + d], a);
            qk_vec[((size_t)b * H_ + h) * KVD + c] = a;
        }
    }
}

// ---------------------------------------------------------------------------
// Kernel B (main): single pass over kv with online softmax.
// Block = 256 threads, handles CHUNK rows of one batch in 16-row LDS tiles.
// Emits per-chunk (m, l, unnormalized ctx[h][512]) partials.
// ---------------------------------------------------------------------------
template <int NC>
__global__ __launch_bounds__(256) void k_attn(const float* __restrict__ kv,
                                              const float* __restrict__ qk_vec,
                                              float* __restrict__ pctx,
                                              float* __restrict__ pml) {
    constexpr int CHUNK = S_ / NC;
    constexpr int T = 16;            // rows per LDS tile
    constexpr int NT = CHUNK / T;
    constexpr int LD = KVD + 4;      // 516: row stride pad -> conflict-free logits reads

    __shared__ float kvt[T * LD];                       // 33 KB
    __shared__ __align__(16) float lg[T][H_];
    __shared__ __align__(16) float wrow[T][H_];
    __shared__ float mh[H_], lh[H_], alpha_s[H_], nmh[H_];

    const int tid = threadIdx.x;
    const int nc = blockIdx.x, b = blockIdx.y;

    if (tid < H_) { mh[tid] = -INFINITY; lh[tid] = 0.f; }

    float ctx[H_][2];
    #pragma unroll
    for (int h = 0; h < H_; ++h) { ctx[h][0] = 0.f; ctx[h][1] = 0.f; }

    const float* qkb = qk_vec + (size_t)b * H_ * KVD;
    const int c0 = tid * 2;          // this thread's 2 owned columns
    const int r_log = tid >> 3, h_log = tid & 7;

    for (int t = 0; t < NT; ++t) {
        __syncthreads();  // protect kvt/wrow from previous tile's readers

        // ---- stage T x 512 floats (32 KB) global -> LDS, coalesced float4
        {
            const float4* src = (const float4*)(kv +
                ((size_t)b * S_ + (size_t)nc * CHUNK + (size_t)t * T) * KVD);
            #pragma unroll
            for (int k = 0; k < 8; ++k) {
                int idx = k * 256 + tid;
                int row = idx >> 7;      // 128 float4 per row
                int c4  = idx & 127;
                float4 v = src[idx];
                *(float4*)&kvt[row * LD + c4 * 4] = v;
            }
        }
        __syncthreads();

        // ---- logits: thread (r,h) for tid<128, dot over 512 cols
        float myl = 0.f;
        if (tid < T * H_) {
            const float* qkh = qkb + (size_t)h_log * KVD;
            const float* kr  = &kvt[r_log * LD];
            float a0 = 0.f, a1 = 0.f, a2 = 0.f, a3 = 0.f;
            for (int c = 0; c < KVD; c += 4) {
                float4 kvv = *(const float4*)&kr[c];
                float4 qv  = *(const float4*)&qkh[c];
                a0 = fmaf(kvv.x, qv.x, a0);
                a1 = fmaf(kvv.y, qv.y, a1);
                a2 = fmaf(kvv.z, qv.z, a2);
                a3 = fmaf(kvv.w, qv.w, a3);
            }
            myl = (a0 + a1) + (a2 + a3);
            lg[r_log][h_log] = myl;
        }
        __syncthreads();

        // ---- online max update (8 threads, one per head)
        if (tid < H_) {
            float tmax = -INFINITY;
            #pragma unroll
            for (int r = 0; r < T; ++r) tmax = fmaxf(tmax, lg[r][tid]);
            float m0 = mh[tid];
            float nm = fmaxf(m0, tmax);
            nmh[tid] = nm;
            alpha_s[tid] = __expf(m0 - nm);  // exp(-inf)=0 on first tile
            mh[tid] = nm;
        }
        __syncthreads();

        // ---- weights
        if (tid < T * H_) {
            wrow[r_log][h_log] = __expf(myl - nmh[h_log]);
        }
        __syncthreads();

        // ---- l update (8 threads) — reads wrow after barrier, no conflict
        if (tid < H_) {
            float s = 0.f;
            #pragma unroll
            for (int r = 0; r < T; ++r) s += wrow[r][tid];
            lh[tid] = fmaf(lh[tid], alpha_s[tid], s);
        }

        // ---- rescale + accumulate: each thread owns 2 columns, all 8 heads
        float al[H_];
        #pragma unroll
        for (int h = 0; h < H_; ++h) al[h] = alpha_s[h];
        #pragma unroll
        for (int h = 0; h < H_; ++h) { ctx[h][0] *= al[h]; ctx[h][1] *= al[h]; }

        for (int r = 0; r < T; ++r) {
            float2 kvv = *(const float2*)&kvt[r * LD + c0];
            float4 w0  = *(const float4*)&wrow[r][0];   // broadcast
            float4 w1  = *(const float4*)&wrow[r][4];   // broadcast
            ctx[0][0] = fmaf(w0.x, kvv.x, ctx[0][0]); ctx[0][1] = fmaf(w0.x, kvv.y, ctx[0][1]);
            ctx[1][0] = fmaf(w0.y, kvv.x, ctx[1][0]); ctx[1][1] = fmaf(w0.y, kvv.y, ctx[1][1]);
            ctx[2][0] = fmaf(w0.z, kvv.x, ctx[2][0]); ctx[2][1] = fmaf(w0.z, kvv.y, ctx[2][1]);
            ctx[3][0] = fmaf(w0.w, kvv.x, ctx[3][0]); ctx[3][1] = fmaf(w0.w, kvv.y, ctx[3][1]);
            ctx[4][0] = fmaf(w1.x, kvv.x, ctx[4][0]); ctx[4][1] = fmaf(w1.x, kvv.y, ctx[4][1]);
            ctx[5][0] = fmaf(w1.y, kvv.x, ctx[5][0]); ctx[5][1] = fmaf(w1.y, kvv.y, ctx[5][1]);
            ctx[6][0] = fmaf(w1.z, kvv.x, ctx[6][0]); ctx[6][1] = fmaf(w1.z, kvv.y, ctx[6][1]);
            ctx[7][0] = fmaf(w1.w, kvv.x, ctx[7][0]); ctx[7][1] = fmaf(w1.w, kvv.y, ctx[7][1]);
        }
    }

    // ---- write per-chunk partials
    size_t base = (((size_t)b * NC + nc) * H_) * KVD;
    #pragma unroll
    for (int h = 0; h < H_; ++h) {
        *(float2*)&pctx[base + (size_t)h * KVD + c0] = make_float2(ctx[h][0], ctx[h][1]);
    }
    if (tid < H_) {
        size_t mlidx = ((size_t)b * NC + nc) * H_ + tid;
        pml[mlidx * 2]     = mh[tid];
        pml[mlidx * 2 + 1] = lh[tid];
    }
}

// ---------------------------------------------------------------------------
// Kernel C: combine per-chunk partials -> normalized ctx_kv[b][h][512]
// ---------------------------------------------------------------------------
template <int NC>
__global__ __launch_bounds__(256) void k_combine(const float* __restrict__ pctx,
                                                 const float* __restrict__ pml,
                                                 float* __restrict__ ctx_kv) {
    int bh = blockIdx.x;
    int b = bh >> 3, h = bh & 7;
    int tid = threadIdx.x;

    float mstar = -INFINITY;
    for (int nc = 0; nc < NC; ++nc)
        mstar = fmaxf(mstar, pml[(((size_t)b * NC + nc) * H_ + h) * 2]);

    float lsum = 0.f, acc0 = 0.f, acc1 = 0.f;
    int c = tid * 2;
    for (int nc = 0; nc < NC; ++nc) {
        size_t mlidx = ((size_t)b * NC + nc) * H_ + h;
        float m = pml[mlidx * 2], l = pml[mlidx * 2 + 1];
        float f = __expf(m - mstar);
        lsum = fmaf(l, f, lsum);
        float2 v = *(const float2*)&pctx[(((size_t)b * NC + nc) * H_ + h) * KVD + c];
        acc0 = fmaf(f, v.x, acc0);
        acc1 = fmaf(f, v.y, acc1);
    }
    float inv = 1.0f / lsum;
    *(float2*)&ctx_kv[((size_t)b * H_ + h) * KVD + c] = make_float2(acc0 * inv, acc1 * inv);
}

// ---------------------------------------------------------------------------
// Kernel D: context = ctx_kv @ Wv + bv (per-head cols), then out = context@Wo + bo
// ---------------------------------------------------------------------------
__global__ __launch_bounds__(512) void k_out(const float* __restrict__ ctx_kv,
                                             const float* __restrict__ Wv,
                                             const float* __restrict__ bv,
                                             const float* __restrict__ Wo,
                                             const float* __restrict__ bo,
                                             float* __restrict__ out) {
    int b = blockIdx.x;
    int e = threadIdx.x;
    int h = e >> 6;  // head of output column e (D=64)
    __shared__ float ctxs[E_];

    float acc = bv[e];
    const float* ck = ctx_kv + ((size_t)b * H_ + h) * KVD;
    for (int c = 0; c < KVD; ++c)
        acc = fmaf(ck[c], Wv[(size_t)c * E_ + e], acc);
    ctxs[e] = acc;
    __syncthreads();

    float o = bo[e];
    for (int i = 0; i < E_; ++i)
        o = fmaf(ctxs[i], Wo[(size_t)i * E_ + e], o);
    out[(size_t)b * E_ + e] = o;
}

// ---------------------------------------------------------------------------
extern "C" void kernel_launch(void* const* d_in, const int* in_sizes, int n_in,
                              void* d_out, int out_size, void* d_ws, size_t ws_size,
                              hipStream_t stream) {
    const float* query = (const float*)d_in[0];
    const float* kv    = (const float*)d_in[1];
    const float* Wq    = (const float*)d_in[2];
    const float* bq    = (const float*)d_in[3];
    const float* Wk    = (const float*)d_in[4];
    // d_in[5] = bk: softmax-invariant constant per (b,h) -> unused
    const float* Wv    = (const float*)d_in[6];
    const float* bv    = (const float*)d_in[7];
    const float* Wo    = (const float*)d_in[8];
    const float* bo    = (const float*)d_in[9];
    float* out = (float*)d_out;
    float* wsf = (float*)d_ws;

    // ws floats needed: qk_vec 65536 + pctx NC*65536 + pml NC*256 + ctx_kv 65536
    auto need_bytes = [](size_t nc) {
        return (131072ull + nc * (65536ull + 256ull)) * 4ull;
    };

    float* qk_vec = wsf;

    k_fold<<<B_, 512, 0, stream>>>(query, Wq, bq, Wk, qk_vec);

    if (ws_size >= need_bytes(64)) {
        constexpr int NC = 64;
        float* pctx   = wsf + 65536;
        float* pml    = pctx + (size_t)NC * 65536;
        float* ctx_kv = pml + (size_t)NC * 256;
        k_attn<NC><<<dim3(NC, B_), 256, 0, stream>>>(kv, qk_vec, pctx, pml);
        k_combine<NC><<<B_ * H_, 256, 0, stream>>>(pctx, pml, ctx_kv);
        k_out<<<B_, 512, 0, stream>>>(ctx_kv, Wv, bv, Wo, bo, out);
    } else if (ws_size >= need_bytes(32)) {
        constexpr int NC = 32;
        float* pctx   = wsf + 65536;
        float* pml    = pctx + (size_t)NC * 65536;
        float* ctx_kv = pml + (size_t)NC * 256;
        k_attn<NC><<<dim3(NC, B_), 256, 0, stream>>>(kv, qk_vec, pctx, pml);
        k_combine<NC><<<B_ * H_, 256, 0, stream>>>(pctx, pml, ctx_kv);
        k_out<<<B_, 512, 0, stream>>>(ctx_kv, Wv, bv, Wo, bo, out);
    } else {
        constexpr int NC = 16;
        float* pctx   = wsf + 65536;
        float* pml    = pctx + (size_t)NC * 65536;
        float* ctx_kv = pml + (size_t)NC * 256;
        k_attn<NC><<<dim3(NC, B_), 256, 0, stream>>>(kv, qk_vec, pctx, pml);
        k_combine<NC><<<B_ * H_, 256, 0, stream>>>(pctx, pml, ctx_kv);
        k_out<<<B_, 512, 0, stream>>>(ctx_kv, Wv, bv, Wo, bo, out);
    }
}

// Round 2
// 467.122 us; speedup vs baseline: 1.8799x; 1.8799x over previous
//
#include <hip/hip_runtime.h>
#include <math.h>

#define B_   16
#define S_   8192
#define KVD  512
#define E_   512
#define H_   8
#define D_   64

// ---------------------------------------------------------------------------
// k_fold: qk_vec[b][h][c] = sum_d q[b][h*64+d] * Wk[c][h*64+d], q scaled by 1/8.
// grid (8 col-chunks, B), 256 thr. Each block redundantly computes q (cheap).
// ---------------------------------------------------------------------------
__global__ __launch_bounds__(256) void k_fold(const float* __restrict__ query,
                                              const float* __restrict__ Wq,
                                              const float* __restrict__ bq,
                                              const float* __restrict__ Wk,
                                              float* __restrict__ qk_vec) {
    const int b = blockIdx.y, cc = blockIdx.x;
    const int tid = threadIdx.x;
    __shared__ float qs[E_];

    const float* qrow = query + (size_t)b * 512;
    #pragma unroll
    for (int i = 0; i < 2; ++i) {
        int e = tid + i * 256;
        float a0 = bq[e], a1 = 0.f, a2 = 0.f, a3 = 0.f;
        for (int k = 0; k < 512; k += 4) {
            a0 = fmaf(qrow[k],     Wq[(size_t)(k)     * E_ + e], a0);
            a1 = fmaf(qrow[k + 1], Wq[(size_t)(k + 1) * E_ + e], a1);
            a2 = fmaf(qrow[k + 2], Wq[(size_t)(k + 2) * E_ + e], a2);
            a3 = fmaf(qrow[k + 3], Wq[(size_t)(k + 3) * E_ + e], a3);
        }
        qs[e] = ((a0 + a1) + (a2 + a3)) * 0.125f;  // 1/sqrt(64)
    }
    __syncthreads();

    #pragma unroll
    for (int i = 0; i < 2; ++i) {
        int idx = tid + i * 256;
        int c = cc * 64 + (idx & 63);
        int h = idx >> 6;  // 0..3 then 4..7
        const float* wkr = Wk + (size_t)c * E_ + h * D_;
        const float* qh  = qs + h * D_;
        float a0 = 0.f, a1 = 0.f, a2 = 0.f, a3 = 0.f;
        #pragma unroll
        for (int d = 0; d < D_; d += 4) {
            a0 = fmaf(qh[d],     wkr[d],     a0);
            a1 = fmaf(qh[d + 1], wkr[d + 1], a1);
            a2 = fmaf(qh[d + 2], wkr[d + 2], a2);
            a3 = fmaf(qh[d + 3], wkr[d + 3], a3);
        }
        qk_vec[((size_t)b * H_ + h) * KVD + c] = (a0 + a1) + (a2 + a3);
    }
}

// ---------------------------------------------------------------------------
// k_attn v2: wave-autonomous online-softmax streaming.
// Block = 256 thr = 4 independent waves; each wave owns RPW rows.
// Lane l owns cols {l*4..l*4+3, 256+l*4..+3}; softmax home head = lane>>3
// (state replicated across the 8 seg lanes). No barriers in the main loop.
// ---------------------------------------------------------------------------
template <int NC>
__global__ __launch_bounds__(256, 2) void k_attn(const float* __restrict__ kv,
                                                 const float* __restrict__ qk_vec,
                                                 float* __restrict__ pctx,
                                                 float* __restrict__ pml) {
    constexpr int CHUNK = S_ / NC;
    constexpr int RPW = CHUNK / 4;    // rows per wave
    constexpr int RB = 4;             // rows per batched iteration
    constexpr int NIT = RPW / RB;
    constexpr int SROW = 68;          // 272 B: 16B-aligned, conflict-free pattern
    constexpr int SPW = RB * H_ * SROW;

    __shared__ __align__(16) float scr[4 * SPW];     // 34816 B partial scratch
    __shared__ __align__(16) float wb[4][RB * H_];   // per-wave weight broadcast
    __shared__ __align__(16) float ab[4][H_];        // per-wave alpha broadcast
    __shared__ __align__(16) float mW[4][H_];
    __shared__ __align__(16) float lW[4][H_];
    __shared__ __align__(16) float cbuf[H_][KVD];    // 16 KB merge buffer

    const int tid = threadIdx.x;
    const int lane = tid & 63;
    const int w = tid >> 6;
    const int b = blockIdx.y, nc = blockIdx.x;
    const int hme = lane >> 3;
    const int seg = lane & 7;

    // qk fragments in registers: qk[h][j]
    float qk[H_][8];
    {
        const float* qb = qk_vec + (size_t)b * H_ * KVD;
        #pragma unroll
        for (int h = 0; h < H_; ++h) {
            float4 v0 = *(const float4*)&qb[h * KVD + lane * 4];
            float4 v1 = *(const float4*)&qb[h * KVD + 256 + lane * 4];
            qk[h][0] = v0.x; qk[h][1] = v0.y; qk[h][2] = v0.z; qk[h][3] = v0.w;
            qk[h][4] = v1.x; qk[h][5] = v1.y; qk[h][6] = v1.z; qk[h][7] = v1.w;
        }
    }

    float ctx[H_][8];
    #pragma unroll
    for (int h = 0; h < H_; ++h)
        #pragma unroll
        for (int j = 0; j < 8; ++j) ctx[h][j] = 0.f;

    float m_run = -INFINITY, l_run = 0.f;

    float* wscr = scr + w * SPW;
    const float* rdb = wscr + hme * SROW + seg * 8;
    const float* kvbase = kv + ((size_t)b * S_ + (size_t)nc * CHUNK + (size_t)w * RPW) * KVD;

    #pragma unroll 1
    for (int it = 0; it < NIT; ++it) {
        // ---- load RB rows straight to registers (coalesced float4 x2 per row)
        float kvr[RB][8];
        #pragma unroll
        for (int r = 0; r < RB; ++r) {
            const float* rowp = kvbase + (size_t)(it * RB + r) * KVD;
            float4 v0 = *(const float4*)&rowp[lane * 4];
            float4 v1 = *(const float4*)&rowp[256 + lane * 4];
            kvr[r][0] = v0.x; kvr[r][1] = v0.y; kvr[r][2] = v0.z; kvr[r][3] = v0.w;
            kvr[r][4] = v1.x; kvr[r][5] = v1.y; kvr[r][6] = v1.z; kvr[r][7] = v1.w;
        }

        // ---- per-lane dot partials, scattered to LDS (all writes batched)
        #pragma unroll
        for (int r = 0; r < RB; ++r) {
            #pragma unroll
            for (int h = 0; h < H_; ++h) {
                float p = 0.f;
                #pragma unroll
                for (int j = 0; j < 8; ++j) p = fmaf(kvr[r][j], qk[h][j], p);
                wscr[(r * H_ + h) * SROW + lane] = p;
            }
        }

        // ---- reduce: lane sums 8 partials of (row r, head hme), butterfly over seg
        float lg[RB];
        #pragma unroll
        for (int r = 0; r < RB; ++r) {
            const float* p = rdb + r * H_ * SROW;
            float4 x = *(const float4*)p;
            float4 y = *(const float4*)(p + 4);
            float s = ((x.x + x.y) + (x.z + x.w)) + ((y.x + y.y) + (y.z + y.w));
            s += __shfl_xor(s, 1);
            s += __shfl_xor(s, 2);
            s += __shfl_xor(s, 4);
            lg[r] = s;  // logit(row it*RB+r, head hme) in all 8 seg lanes
        }

        // ---- per-lane online softmax for home head
        float bmax = lg[0];
        #pragma unroll
        for (int r = 1; r < RB; ++r) bmax = fmaxf(bmax, lg[r]);
        float nm = fmaxf(m_run, bmax);
        float alpha = __expf(m_run - nm);   // exp(-inf)=0 on first iter
        m_run = nm;
        float wj[RB], sw = 0.f;
        #pragma unroll
        for (int r = 0; r < RB; ++r) { wj[r] = __expf(lg[r] - nm); sw += wj[r]; }
        l_run = fmaf(l_run, alpha, sw);

        // ---- broadcast weights + alpha to all lanes (same-wave LDS, in-order)
        if (seg == 0) {
            #pragma unroll
            for (int r = 0; r < RB; ++r) wb[w][r * H_ + hme] = wj[r];
            ab[w][hme] = alpha;
        }
        float4 A0 = *(const float4*)&ab[w][0];
        float4 A1 = *(const float4*)&ab[w][4];
        float al[8] = {A0.x, A0.y, A0.z, A0.w, A1.x, A1.y, A1.z, A1.w};
        #pragma unroll
        for (int h = 0; h < H_; ++h)
            #pragma unroll
            for (int j = 0; j < 8; ++j) ctx[h][j] *= al[h];

        #pragma unroll
        for (int r = 0; r < RB; ++r) {
            float4 W0 = *(const float4*)&wb[w][r * H_];
            float4 W1 = *(const float4*)&wb[w][r * H_ + 4];
            float wv[8] = {W0.x, W0.y, W0.z, W0.w, W1.x, W1.y, W1.z, W1.w};
            #pragma unroll
            for (int h = 0; h < H_; ++h)
                #pragma unroll
                for (int j = 0; j < 8; ++j)
                    ctx[h][j] = fmaf(wv[h], kvr[r][j], ctx[h][j]);
        }
    }

    // ---- end-of-block merge of the 4 waves (online-softmax combine)
    if (seg == 0) { mW[w][hme] = m_run; lW[w][hme] = l_run; }
    __syncthreads();

    float Mh[H_];
    #pragma unroll
    for (int h = 0; h < H_; ++h)
        Mh[h] = fmaxf(fmaxf(mW[0][h], mW[1][h]), fmaxf(mW[2][h], mW[3][h]));

    if (w == 0) {
        #pragma unroll
        for (int h = 0; h < H_; ++h) {
            float f = __expf(mW[0][h] - Mh[h]);
            #pragma unroll
            for (int j = 0; j < 8; ++j) ctx[h][j] *= f;
        }
    }
    #pragma unroll 1
    for (int src = 1; src < 4; ++src) {
        if (w == src) {
            #pragma unroll
            for (int h = 0; h < H_; ++h) {
                *(float4*)&cbuf[h][lane * 4]       = make_float4(ctx[h][0], ctx[h][1], ctx[h][2], ctx[h][3]);
                *(float4*)&cbuf[h][256 + lane * 4] = make_float4(ctx[h][4], ctx[h][5], ctx[h][6], ctx[h][7]);
            }
        }
        __syncthreads();
        if (w == 0) {
            #pragma unroll
            for (int h = 0; h < H_; ++h) {
                float f = __expf(mW[src][h] - Mh[h]);
                float4 c0 = *(const float4*)&cbuf[h][lane * 4];
                float4 c1 = *(const float4*)&cbuf[h][256 + lane * 4];
                ctx[h][0] = fmaf(f, c0.x, ctx[h][0]);
                ctx[h][1] = fmaf(f, c0.y, ctx[h][1]);
                ctx[h][2] = fmaf(f, c0.z, ctx[h][2]);
                ctx[h][3] = fmaf(f, c0.w, ctx[h][3]);
                ctx[h][4] = fmaf(f, c1.x, ctx[h][4]);
                ctx[h][5] = fmaf(f, c1.y, ctx[h][5]);
                ctx[h][6] = fmaf(f, c1.z, ctx[h][6]);
                ctx[h][7] = fmaf(f, c1.w, ctx[h][7]);
            }
        }
        __syncthreads();
    }

    if (w == 0) {
        size_t base = (((size_t)b * NC + nc) * H_) * KVD;
        #pragma unroll
        for (int h = 0; h < H_; ++h) {
            *(float4*)&pctx[base + h * KVD + lane * 4] =
                make_float4(ctx[h][0], ctx[h][1], ctx[h][2], ctx[h][3]);
            *(float4*)&pctx[base + h * KVD + 256 + lane * 4] =
                make_float4(ctx[h][4], ctx[h][5], ctx[h][6], ctx[h][7]);
        }
    }
    if (tid < H_) {
        float M = fmaxf(fmaxf(mW[0][tid], mW[1][tid]), fmaxf(mW[2][tid], mW[3][tid]));
        float L = 0.f;
        #pragma unroll
        for (int ww = 0; ww < 4; ++ww) L += __expf(mW[ww][tid] - M) * lW[ww][tid];
        size_t mlidx = ((size_t)b * NC + nc) * H_ + tid;
        pml[mlidx * 2]     = M;
        pml[mlidx * 2 + 1] = L;
    }
}

// ---------------------------------------------------------------------------
// k_combine: merge per-chunk partials -> normalized ctx_kv[b][h][512]
// ---------------------------------------------------------------------------
template <int NC>
__global__ __launch_bounds__(256) void k_combine(const float* __restrict__ pctx,
                                                 const float* __restrict__ pml,
                                                 float* __restrict__ ctx_kv) {
    int bh = blockIdx.x;
    int b = bh >> 3, h = bh & 7;
    int tid = threadIdx.x;

    float mstar = -INFINITY;
    for (int nc = 0; nc < NC; ++nc)
        mstar = fmaxf(mstar, pml[(((size_t)b * NC + nc) * H_ + h) * 2]);

    float lsum = 0.f, acc0 = 0.f, acc1 = 0.f;
    int c = tid * 2;
    for (int nc = 0; nc < NC; ++nc) {
        size_t mlidx = ((size_t)b * NC + nc) * H_ + h;
        float m = pml[mlidx * 2], l = pml[mlidx * 2 + 1];
        float f = __expf(m - mstar);
        lsum = fmaf(l, f, lsum);
        float2 v = *(const float2*)&pctx[(((size_t)b * NC + nc) * H_ + h) * KVD + c];
        acc0 = fmaf(f, v.x, acc0);
        acc1 = fmaf(f, v.y, acc1);
    }
    float inv = 1.0f / lsum;
    *(float2*)&ctx_kv[((size_t)b * H_ + h) * KVD + c] = make_float2(acc0 * inv, acc1 * inv);
}

// ---------------------------------------------------------------------------
// k_out: context = ctx_kv @ Wv + bv, out = context @ Wo + bo.
// grid (4 e-chunks, B), 512 thr. Phase 1 computes full context (not redundant
// within block), phase 2 does 128 outputs with 4-way split-K.
// ---------------------------------------------------------------------------
__global__ __launch_bounds__(512) void k_out(const float* __restrict__ ctx_kv,
                                             const float* __restrict__ Wv,
                                             const float* __restrict__ bv,
                                             const float* __restrict__ Wo,
                                             const float* __restrict__ bo,
                                             float* __restrict__ out) {
    const int b = blockIdx.y, ec = blockIdx.x;
    const int tid = threadIdx.x;
    __shared__ float ctxs[E_];
    __shared__ float psum[4][128];

    {
        int e = tid, h = e >> 6;
        const float* ck = ctx_kv + ((size_t)b * H_ + h) * KVD;
        float a0 = bv[e], a1 = 0.f, a2 = 0.f, a3 = 0.f;
        for (int c = 0; c < KVD; c += 4) {
            a0 = fmaf(ck[c],     Wv[(size_t)(c)     * E_ + e], a0);
            a1 = fmaf(ck[c + 1], Wv[(size_t)(c + 1) * E_ + e], a1);
            a2 = fmaf(ck[c + 2], Wv[(size_t)(c + 2) * E_ + e], a2);
            a3 = fmaf(ck[c + 3], Wv[(size_t)(c + 3) * E_ + e], a3);
        }
        ctxs[e] = (a0 + a1) + (a2 + a3);
    }
    __syncthreads();
    {
        int el = tid & 127, q = tid >> 7;
        int e = ec * 128 + el;
        const float* cs = ctxs + q * 128;
        const float* wo = Wo + (size_t)q * 128 * E_ + e;
        float a0 = 0.f, a1 = 0.f, a2 = 0.f, a3 = 0.f;
        for (int k = 0; k < 128; k += 4) {
            a0 = fmaf(cs[k],     wo[(size_t)(k)     * E_], a0);
            a1 = fmaf(cs[k + 1], wo[(size_t)(k + 1) * E_], a1);
            a2 = fmaf(cs[k + 2], wo[(size_t)(k + 2) * E_], a2);
            a3 = fmaf(cs[k + 3], wo[(size_t)(k + 3) * E_], a3);
        }
        psum[q][el] = (a0 + a1) + (a2 + a3);
    }
    __syncthreads();
    if (tid < 128) {
        int e = ec * 128 + tid;
        out[(size_t)b * E_ + e] =
            bo[e] + ((psum[0][tid] + psum[1][tid]) + (psum[2][tid] + psum[3][tid]));
    }
}

// ---------------------------------------------------------------------------
extern "C" void kernel_launch(void* const* d_in, const int* in_sizes, int n_in,
                              void* d_out, int out_size, void* d_ws, size_t ws_size,
                              hipStream_t stream) {
    const float* query = (const float*)d_in[0];
    const float* kv    = (const float*)d_in[1];
    const float* Wq    = (const float*)d_in[2];
    const float* bq    = (const float*)d_in[3];
    const float* Wk    = (const float*)d_in[4];
    // d_in[5] = bk: softmax-invariant per (b,h) -> unused
    const float* Wv    = (const float*)d_in[6];
    const float* bv    = (const float*)d_in[7];
    const float* Wo    = (const float*)d_in[8];
    const float* bo    = (const float*)d_in[9];
    float* out = (float*)d_out;
    float* wsf = (float*)d_ws;

    auto need_bytes = [](size_t nc) {
        return (131072ull + nc * (65536ull + 256ull)) * 4ull;
    };

    float* qk_vec = wsf;
    k_fold<<<dim3(8, B_), 256, 0, stream>>>(query, Wq, bq, Wk, qk_vec);

    if (ws_size >= need_bytes(64)) {
        constexpr int NC = 64;
        float* pctx   = wsf + 65536;
        float* pml    = pctx + (size_t)NC * 65536;
        float* ctx_kv = pml + (size_t)NC * 256;
        k_attn<NC><<<dim3(NC, B_), 256, 0, stream>>>(kv, qk_vec, pctx, pml);
        k_combine<NC><<<B_ * H_, 256, 0, stream>>>(pctx, pml, ctx_kv);
        k_out<<<dim3(4, B_), 512, 0, stream>>>(ctx_kv, Wv, bv, Wo, bo, out);
    } else if (ws_size >= need_bytes(32)) {
        constexpr int NC = 32;
        float* pctx   = wsf + 65536;
        float* pml    = pctx + (size_t)NC * 65536;
        float* ctx_kv = pml + (size_t)NC * 256;
        k_attn<NC><<<dim3(NC, B_), 256, 0, stream>>>(kv, qk_vec, pctx, pml);
        k_combine<NC><<<B_ * H_, 256, 0, stream>>>(pctx, pml, ctx_kv);
        k_out<<<dim3(4, B_), 512, 0, stream>>>(ctx_kv, Wv, bv, Wo, bo, out);
    } else {
        constexpr int NC = 16;
        float* pctx   = wsf + 65536;
        float* pml    = pctx + (size_t)NC * 65536;
        float* ctx_kv = pml + (size_t)NC * 256;
        k_attn<NC><<<dim3(NC, B_), 256, 0, stream>>>(kv, qk_vec, pctx, pml);
        k_combine<NC><<<B_ * H_, 256, 0, stream>>>(pctx, pml, ctx_kv);
        k_out<<<dim3(4, B_), 512, 0, stream>>>(ctx_kv, Wv, bv, Wo, bo, out);
    }
}